// Round 2
// baseline (208.797 us; speedup 1.0000x reference)
//
#include <hip/hip_runtime.h>
#include <hip/hip_bf16.h>

// CorrelatorK3: B=8, N=256, D=64, F=64
// Stage 1 (wave-specialized, operand-swapped MFMA):
//   A[p,kk]  = (rbf0[p]·Q0w+Q0b) * (rbfd[p]·Qw+Qb)   (bf16, f-permuted kk)
//   Bm[p,kk] = (rbf0[p]·R0w+R0b) * (rbfd[p]·Rw+Rb)   (bf16, f-permuted kk)
//   kk = kg*16 + ft*4 + r  <->  f = ft*16 + kg*4 + r  (same perm both bufs,
//   so the stage-2 contraction over f is unchanged)
// Stage 2: C[b,n,j] = 0.02 * sum_{i,kk} A[b,n,i,kk] * Bm[b,i,j,kk]

typedef __bf16 bf16x8 __attribute__((ext_vector_type(8)));
typedef float  f32x4  __attribute__((ext_vector_type(4)));
typedef int    i32x4  __attribute__((ext_vector_type(4)));
typedef unsigned short u16;
typedef u16    u16x8  __attribute__((ext_vector_type(8)));

static __device__ __forceinline__ __bf16 f2bf(float x) {
  union { __hip_bfloat16 h; __bf16 b; } u;
  u.h = __float2bfloat16(x);
  return u.b;
}
static __device__ __forceinline__ u16 f2bfu(float x) {
  union { __hip_bfloat16 h; u16 s; } u;
  u.h = __float2bfloat16(x);
  return u.s;
}
static __device__ __forceinline__ float bfu2f(u16 s) {
  union { unsigned int u; float f; } v;
  v.u = ((unsigned int)s) << 16;
  return v.f;
}

// ---------------------------------------------------------------- stage 1 ---
// Grid: 1024 blocks x 256 thr. Block = 4 waves: (role = wave>>1) 0:Q->A, 1:R->Bm;
// sub = wave&1 picks tile t = blockIdx*2 + sub + iter*2048. Twin roles share a
// tile -> second reader hits L1/L2; HBM fetch stays ~1x.
__global__ __launch_bounds__(256, 3) void k_phase1(
    const float* __restrict__ rbf0, const float* __restrict__ rbfd,
    const float* __restrict__ Q0w, const float* __restrict__ Q0b,
    const float* __restrict__ Qw,  const float* __restrict__ Qb,
    const float* __restrict__ R0w, const float* __restrict__ R0b,
    const float* __restrict__ Rw,  const float* __restrict__ Rb,
    u16* __restrict__ Aout, u16* __restrict__ Bout)
{
  const int lane = threadIdx.x & 63;
  const int wave = threadIdx.x >> 6;
  const int fr   = lane & 15;   // position-in-tile (MFMA col) / weight f-row
  const int kg   = lane >> 4;   // k-group
  const int role = wave >> 1;   // 0: Q-path (A), 1: R-path (Bm)
  const int sub  = wave & 1;

  const float* W0 = role ? R0w : Q0w;   // multiplies rbf_0
  const float* W1 = role ? Rw  : Qw;    // multiplies rbf_d
  const float* B0 = role ? R0b : Q0b;
  const float* B1 = role ? Rb  : Qb;
  u16* __restrict__ Out = role ? Bout : Aout;

  // Weight A-frags: lane holds W[ft*16+fr][kt*32+kg*8+j]  (2 matrices, 64 VGPR)
  bf16x8 wf0[2][4], wf1[2][4];
#pragma unroll
  for (int kt = 0; kt < 2; ++kt)
#pragma unroll
    for (int ft = 0; ft < 4; ++ft) {
      const float* p0 = W0 + (ft * 16 + fr) * 64 + kt * 32 + kg * 8;
      const float* p1 = W1 + (ft * 16 + fr) * 64 + kt * 32 + kg * 8;
      f32x4 a = *(const f32x4*)p0, b = *(const f32x4*)(p0 + 4);
      f32x4 c = *(const f32x4*)p1, d = *(const f32x4*)(p1 + 4);
      bf16x8 w0, w1;
#pragma unroll
      for (int j = 0; j < 4; ++j) {
        w0[j] = f2bf(a[j]); w0[j + 4] = f2bf(b[j]);
        w1[j] = f2bf(c[j]); w1[j + 4] = f2bf(d[j]);
      }
      wf0[kt][ft] = w0; wf1[kt][ft] = w1;
    }

  // Bias packed bf16 in permuted order idx = ft*4+r  (value b[ft*16+kg*4+r])
  u16x8 pb0[2], pb1[2];
#pragma unroll
  for (int ft = 0; ft < 4; ++ft)
#pragma unroll
    for (int r = 0; r < 4; ++r) {
      int idx = ft * 4 + r;
      pb0[idx >> 3][idx & 7] = f2bfu(B0[ft * 16 + kg * 4 + r]);
      pb1[idx >> 3][idx & 7] = f2bfu(B1[ft * 16 + kg * 4 + r]);
    }

  const int NT = 32768;
  const int stride = gridDim.x * 2;
  int t = blockIdx.x * 2 + sub;

  f32x4 cur[8];
  {
    const float* x0 = rbf0 + (size_t)t * 1024 + fr * 64 + kg * 8;
    const float* xd = rbfd + (size_t)t * 1024 + fr * 64 + kg * 8;
    cur[0] = *(const f32x4*)(x0);      cur[1] = *(const f32x4*)(x0 + 4);
    cur[2] = *(const f32x4*)(x0 + 32); cur[3] = *(const f32x4*)(x0 + 36);
    cur[4] = *(const f32x4*)(xd);      cur[5] = *(const f32x4*)(xd + 4);
    cur[6] = *(const f32x4*)(xd + 32); cur[7] = *(const f32x4*)(xd + 36);
  }

  while (t < NT) {
    // cur -> bf16 frags (frees cur's 32 VGPRs before nxt is live)
    bf16x8 x0f[2], xdf[2];
#pragma unroll
    for (int j = 0; j < 4; ++j) {
      x0f[0][j] = f2bf(cur[0][j]); x0f[0][j + 4] = f2bf(cur[1][j]);
      x0f[1][j] = f2bf(cur[2][j]); x0f[1][j + 4] = f2bf(cur[3][j]);
      xdf[0][j] = f2bf(cur[4][j]); xdf[0][j + 4] = f2bf(cur[5][j]);
      xdf[1][j] = f2bf(cur[6][j]); xdf[1][j + 4] = f2bf(cur[7][j]);
    }

    // prefetch next tile (overlaps MFMA + epilogue + store below)
    int tn = t + stride;
    f32x4 nxt[8];
    if (tn < NT) {
      const float* x0 = rbf0 + (size_t)tn * 1024 + fr * 64 + kg * 8;
      const float* xd = rbfd + (size_t)tn * 1024 + fr * 64 + kg * 8;
      nxt[0] = *(const f32x4*)(x0);      nxt[1] = *(const f32x4*)(x0 + 4);
      nxt[2] = *(const f32x4*)(x0 + 32); nxt[3] = *(const f32x4*)(x0 + 36);
      nxt[4] = *(const f32x4*)(xd);      nxt[5] = *(const f32x4*)(xd + 4);
      nxt[6] = *(const f32x4*)(xd + 32); nxt[7] = *(const f32x4*)(xd + 36);
    }

    // acc init = bias (broadcast across the 4 positions in the reg column)
    f32x4 acc0[4], acc1[4];
#pragma unroll
    for (int ft = 0; ft < 4; ++ft)
#pragma unroll
      for (int r = 0; r < 4; ++r) {
        int idx = ft * 4 + r;
        acc0[ft][r] = bfu2f(pb0[idx >> 3][idx & 7]);
        acc1[ft][r] = bfu2f(pb1[idx >> 3][idx & 7]);
      }

    // D = W · X : D[row=f_local][col=p]  -> lane owns col p=fr, f=ft*16+kg*4+r
#pragma unroll
    for (int kt = 0; kt < 2; ++kt)
#pragma unroll
      for (int ft = 0; ft < 4; ++ft) {
        acc0[ft] = __builtin_amdgcn_mfma_f32_16x16x32_bf16(wf0[kt][ft], x0f[kt], acc0[ft], 0, 0, 0);
        acc1[ft] = __builtin_amdgcn_mfma_f32_16x16x32_bf16(wf1[kt][ft], xdf[kt], acc1[ft], 0, 0, 0);
      }

    // product + pack: 16 contiguous ushorts per lane at [p*64 + kg*16]
    u16x8 o[2];
#pragma unroll
    for (int ft = 0; ft < 4; ++ft)
#pragma unroll
      for (int r = 0; r < 4; ++r) {
        int idx = ft * 4 + r;
        o[idx >> 3][idx & 7] = f2bfu(acc0[ft][r] * acc1[ft][r]);
      }
    u16* dst = Out + ((size_t)t * 16 + fr) * 64 + kg * 16;
    *(u16x8*)dst       = o[0];
    *(u16x8*)(dst + 8) = o[1];

#pragma unroll
    for (int i = 0; i < 8; ++i) cur[i] = nxt[i];
    t = tn;
  }
}

// ---------------------------------------------------------------- stage 2 ---
// Grid: 256 blocks = 8 b * 2 nt * 2 jt * 8 kc. Block = 4 waves (2x2), tile 128x128.
__global__ __launch_bounds__(256, 2) void k_phase2(
    const u16* __restrict__ A, const u16* __restrict__ Bm,
    float* __restrict__ C)
{
  __shared__ __align__(16) u16 Alds[128 * 64];
  __shared__ __align__(16) u16 Blds[128 * 64];

  const int tid  = threadIdx.x;
  const int lane = tid & 63;
  const int wave = tid >> 6;
  const int fr   = lane & 15;
  const int kg   = lane >> 4;

  const int bid = blockIdx.x;
  const int kc = bid & 7;
  const int jt = (bid >> 3) & 1;
  const int nt = (bid >> 4) & 1;
  const int b  = bid >> 5;
  const int n0 = nt * 128, j0 = jt * 128;
  const int wr = wave >> 1, wc = wave & 1;

  const u16* Ab = A  + (size_t)b * 4194304;
  const u16* Bb = Bm + (size_t)b * 4194304;

  f32x4 acc[4][4];
#pragma unroll
  for (int mt = 0; mt < 4; ++mt)
#pragma unroll
    for (int nn = 0; nn < 4; ++nn) {
      acc[mt][nn][0] = 0.f; acc[mt][nn][1] = 0.f; acc[mt][nn][2] = 0.f; acc[mt][nn][3] = 0.f;
    }

  for (int ii = 0; ii < 32; ++ii) {
    const int i = kc * 32 + ii;

    i32x4 va[4], vb[4];
#pragma unroll
    for (int rep = 0; rep < 4; ++rep) {
      int c = tid + rep * 256;
      int row = c >> 3, ch = c & 7;
      va[rep] = *(const i32x4*)(Ab + (size_t)(n0 + row) * 16384 + (size_t)i * 64 + ch * 8);
      vb[rep] = *(const i32x4*)(Bb + (size_t)i * 16384 + (size_t)(j0 + row) * 64 + ch * 8);
    }
    __syncthreads();
#pragma unroll
    for (int rep = 0; rep < 4; ++rep) {
      int c = tid + rep * 256;
      int row = c >> 3, ch = c & 7;
      int sw = ch ^ (row & 7);
      *(i32x4*)&Alds[row * 64 + sw * 8] = va[rep];
      *(i32x4*)&Blds[row * 64 + sw * 8] = vb[rep];
    }
    __syncthreads();

#pragma unroll
    for (int ks = 0; ks < 2; ++ks) {
      bf16x8 af[4], bfv[4];
#pragma unroll
      for (int mt = 0; mt < 4; ++mt) {
        int row = wr * 64 + mt * 16 + fr;
        int sw = (ks * 4 + kg) ^ (row & 7);
        af[mt] = *(const bf16x8*)&Alds[row * 64 + sw * 8];
      }
#pragma unroll
      for (int nn = 0; nn < 4; ++nn) {
        int row = wc * 64 + nn * 16 + fr;
        int sw = (ks * 4 + kg) ^ (row & 7);
        bfv[nn] = *(const bf16x8*)&Blds[row * 64 + sw * 8];
      }
#pragma unroll
      for (int mt = 0; mt < 4; ++mt)
#pragma unroll
        for (int nn = 0; nn < 4; ++nn)
          acc[mt][nn] = __builtin_amdgcn_mfma_f32_16x16x32_bf16(af[mt], bfv[nn], acc[mt][nn], 0, 0, 0);
    }
  }

  float* Cb = C + ((size_t)b << 16);
#pragma unroll
  for (int mt = 0; mt < 4; ++mt)
#pragma unroll
    for (int nn = 0; nn < 4; ++nn)
#pragma unroll
      for (int r = 0; r < 4; ++r) {
        int n = n0 + wr * 64 + mt * 16 + kg * 4 + r;
        int j = j0 + wc * 64 + nn * 16 + fr;
        atomicAdd(&Cb[n * 256 + j], acc[mt][nn][r] * 0.02f);
      }
}

// ------------------------------------------------------------------ launch --
extern "C" void kernel_launch(void* const* d_in, const int* in_sizes, int n_in,
                              void* d_out, int out_size, void* d_ws, size_t ws_size,
                              hipStream_t stream)
{
  const float* rbf0 = (const float*)d_in[0];
  const float* rbfd = (const float*)d_in[1];
  const float* Q0w  = (const float*)d_in[2];
  const float* Q0b  = (const float*)d_in[3];
  const float* Qw   = (const float*)d_in[4];
  const float* Qb   = (const float*)d_in[5];
  const float* R0w  = (const float*)d_in[6];
  const float* R0b  = (const float*)d_in[7];
  const float* Rw   = (const float*)d_in[8];
  const float* Rb   = (const float*)d_in[9];
  float* out = (float*)d_out;

  u16* Abuf = (u16*)d_ws;
  u16* Bbuf = Abuf + (size_t)33554432;

  hipMemsetAsync(d_out, 0, (size_t)out_size * sizeof(float), stream);
  hipLaunchKernelGGL(k_phase1, dim3(1024), dim3(256), 0, stream,
                     rbf0, rbfd, Q0w, Q0b, Qw, Qb, R0w, R0b, Rw, Rb, Abuf, Bbuf);
  hipLaunchKernelGGL(k_phase2, dim3(256), dim3(256), 0, stream, Abuf, Bbuf, out);
}

// Round 4
// 137.172 us; speedup vs baseline: 1.5222x; 1.5222x over previous
//
#include <hip/hip_runtime.h>
#include <hip/hip_bf16.h>

// CorrelatorK3: B=8, N=256, D=64, F=64
// Stage 1 (LDS-staged, coalesced, role-split waves):
//   A[p,kk]  = (rbf0[p]·Q0w+Q0b) * (rbfd[p]·Qw+Qb)   (bf16, f-permuted kk)
//   Bm[p,kk] = (rbf0[p]·R0w+R0b) * (rbfd[p]·Rw+Rb)   (bf16, f-permuted kk)
//   kk = kg*16 + ft*4 + r  <->  f = ft*16 + kg*4 + r (same perm both bufs)
// Stage 2: C[b,n,j] = 0.02 * sum_{i,kk} A[b,n,i,kk] * Bm[b,i,j,kk]

typedef __bf16 bf16x8 __attribute__((ext_vector_type(8)));
typedef float  f32x4  __attribute__((ext_vector_type(4)));
typedef int    i32x4  __attribute__((ext_vector_type(4)));
typedef unsigned short u16;
typedef u16    u16x8  __attribute__((ext_vector_type(8)));

static __device__ __forceinline__ __bf16 f2bf(float x) {
  union { __hip_bfloat16 h; __bf16 b; } u;
  u.h = __float2bfloat16(x);
  return u.b;
}
static __device__ __forceinline__ u16 f2bfu(float x) {
  union { __hip_bfloat16 h; u16 s; } u;
  u.h = __float2bfloat16(x);
  return u.s;
}
static __device__ __forceinline__ float bfu2f(u16 s) {
  union { unsigned int u; float f; } v;
  v.u = ((unsigned int)s) << 16;
  return v.f;
}

// ---------------------------------------------------------------- stage 1 ---
// Grid 2048 x 256thr (4 waves). Block-tile = 32 positions (8 KB x0 + 8 KB xd).
// Waves: role = wave>>1 (0:Q->A, 1:R->Bm), s = wave&1 (16-pos sub-tile).
// Global loads: lane tid reads chunk tid (16B) -> fully coalesced 4KB/instr.
// LDS layout: [row(pos)][chunk c] stored at chunk (c ^ (row&15)) -> bank-minimal
// ds_write_b128 and ds_read_b128 on both sides.
// Pipeline: ds_write(cur) ; prefetch-load(next) ; lgkm0+raw-barrier ; compute.
// Double-buffer safety: a wave's set-S reads complete before its own
// lgkmcnt(0) at the NEXT barrier; set-S is only rewritten after that barrier.
__global__ __launch_bounds__(256, 3) void k_phase1(
    const float* __restrict__ rbf0, const float* __restrict__ rbfd,
    const float* __restrict__ Q0w, const float* __restrict__ Q0b,
    const float* __restrict__ Qw,  const float* __restrict__ Qb,
    const float* __restrict__ R0w, const float* __restrict__ R0b,
    const float* __restrict__ Rw,  const float* __restrict__ Rb,
    u16* __restrict__ Aout, u16* __restrict__ Bout)
{
  __shared__ __align__(16) float ldsA[2][2048];
  __shared__ __align__(16) float ldsB[2][2048];

  const int tid  = threadIdx.x;
  const int lane = tid & 63;
  const int wave = tid >> 6;
  const int fr   = lane & 15;
  const int kg   = lane >> 4;
  const int role = wave >> 1;
  const int s    = wave & 1;

  const float* W0 = role ? R0w : Q0w;   // multiplies rbf_0
  const float* W1 = role ? Rw  : Qw;    // multiplies rbf_d
  const float* B0 = role ? R0b : Q0b;
  const float* B1 = role ? Rb  : Qb;
  u16* __restrict__ Out = role ? Bout : Aout;

  // Weight A-frags: lane holds W[ft*16+fr][kt*32+kg*8+j]  (2 matrices, 64 VGPR)
  bf16x8 wf0[2][4], wf1[2][4];
#pragma unroll
  for (int kt = 0; kt < 2; ++kt)
#pragma unroll
    for (int ft = 0; ft < 4; ++ft) {
      const float* p0 = W0 + (ft * 16 + fr) * 64 + kt * 32 + kg * 8;
      const float* p1 = W1 + (ft * 16 + fr) * 64 + kt * 32 + kg * 8;
      f32x4 a = *(const f32x4*)p0, b = *(const f32x4*)(p0 + 4);
      f32x4 c = *(const f32x4*)p1, d = *(const f32x4*)(p1 + 4);
      bf16x8 w0v, w1v;
#pragma unroll
      for (int j = 0; j < 4; ++j) {
        w0v[j] = f2bf(a[j]); w0v[j + 4] = f2bf(b[j]);
        w1v[j] = f2bf(c[j]); w1v[j + 4] = f2bf(d[j]);
      }
      wf0[kt][ft] = w0v; wf1[kt][ft] = w1v;
    }

  // Bias, permuted idx = ft*4+r  (value b[ft*16+kg*4+r]), packed bf16
  u16x8 pb0[2], pb1[2];
#pragma unroll
  for (int ft = 0; ft < 4; ++ft)
#pragma unroll
    for (int r = 0; r < 4; ++r) {
      int idx = ft * 4 + r;
      pb0[idx >> 3][idx & 7] = f2bfu(B0[ft * 16 + kg * 4 + r]);
      pb1[idx >> 3][idx & 7] = f2bfu(B1[ft * 16 + kg * 4 + r]);
    }

  // swizzled ds_write chunk indices for this thread's two chunks per array
  const int g0 = tid, g1 = 256 + tid;
  const int w0c = ((g0 >> 4) << 4) | ((g0 & 15) ^ ((g0 >> 4) & 15));
  const int w1c = ((g1 >> 4) << 4) | ((g1 & 15) ^ ((g1 >> 4) & 15));

  const int NBT = 16384;           // 32-position tiles
  const int gstride = gridDim.x;   // 2048
  int bt = blockIdx.x;

  // prologue: load tile bt
  f32x4 v0a, v0b, v1a, v1b;
  {
    const float* p0 = rbf0 + (size_t)bt * 2048;
    const float* p1 = rbfd + (size_t)bt * 2048;
    v0a = *(const f32x4*)(p0 + tid * 4);
    v0b = *(const f32x4*)(p0 + 1024 + tid * 4);
    v1a = *(const f32x4*)(p1 + tid * 4);
    v1b = *(const f32x4*)(p1 + 1024 + tid * 4);
  }

  const int NIT = NBT / 2048;      // 8 iterations (grid must be 2048)
  for (int it = 0; it < NIT; ++it) {
    const int set = it & 1;
    const int cbt = bt;

    // a) stage current tile to LDS (compiler inserts vmcnt for v* defs)
    *(f32x4*)&ldsA[set][w0c * 4] = v0a;
    *(f32x4*)&ldsA[set][w1c * 4] = v0b;
    *(f32x4*)&ldsB[set][w0c * 4] = v1a;
    *(f32x4*)&ldsB[set][w1c * 4] = v1b;

    // b) prefetch next tile (stays in flight across the barrier)
    int btn = bt + gstride;
    int btl = (btn < NBT) ? btn : 0;
    {
      const float* p0 = rbf0 + (size_t)btl * 2048;
      const float* p1 = rbfd + (size_t)btl * 2048;
      v0a = *(const f32x4*)(p0 + tid * 4);
      v0b = *(const f32x4*)(p0 + 1024 + tid * 4);
      v1a = *(const f32x4*)(p1 + tid * 4);
      v1b = *(const f32x4*)(p1 + 1024 + tid * 4);
    }

    // c) LDS writes visible to all waves; do NOT drain vmcnt (prefetch!)
    asm volatile("s_waitcnt lgkmcnt(0)" ::: "memory");
    __builtin_amdgcn_s_barrier();
    __builtin_amdgcn_sched_barrier(0);

    // d) compute: frags from LDS (swizzled), MFMA, product, store
    const int row = s * 16 + fr;   // row&15 == fr
    f32x4 ra[4], rb[4];
#pragma unroll
    for (int kt = 0; kt < 2; ++kt)
#pragma unroll
      for (int h = 0; h < 2; ++h) {
        int c = kt * 8 + kg * 2 + h;
        int chunk = (row << 4) | (c ^ fr);
        ra[kt * 2 + h] = *(const f32x4*)&ldsA[set][chunk * 4];
        rb[kt * 2 + h] = *(const f32x4*)&ldsB[set][chunk * 4];
      }

    bf16x8 x0f[2], xdf[2];
#pragma unroll
    for (int kt = 0; kt < 2; ++kt)
#pragma unroll
      for (int j = 0; j < 4; ++j) {
        x0f[kt][j]     = f2bf(ra[kt * 2][j]);
        x0f[kt][j + 4] = f2bf(ra[kt * 2 + 1][j]);
        xdf[kt][j]     = f2bf(rb[kt * 2][j]);
        xdf[kt][j + 4] = f2bf(rb[kt * 2 + 1][j]);
      }

    f32x4 acc0[4], acc1[4];
#pragma unroll
    for (int ft = 0; ft < 4; ++ft)
#pragma unroll
      for (int r = 0; r < 4; ++r) {
        int idx = ft * 4 + r;
        acc0[ft][r] = bfu2f(pb0[idx >> 3][idx & 7]);
        acc1[ft][r] = bfu2f(pb1[idx >> 3][idx & 7]);
      }

#pragma unroll
    for (int kt = 0; kt < 2; ++kt)
#pragma unroll
      for (int ft = 0; ft < 4; ++ft) {
        acc0[ft] = __builtin_amdgcn_mfma_f32_16x16x32_bf16(wf0[kt][ft], x0f[kt], acc0[ft], 0, 0, 0);
        acc1[ft] = __builtin_amdgcn_mfma_f32_16x16x32_bf16(wf1[kt][ft], xdf[kt], acc1[ft], 0, 0, 0);
      }

    u16x8 o0, o1;
#pragma unroll
    for (int ft = 0; ft < 4; ++ft)
#pragma unroll
      for (int r = 0; r < 4; ++r) {
        int idx = ft * 4 + r;
        float v = acc0[ft][r] * acc1[ft][r];
        if (idx < 8) o0[idx & 7] = f2bfu(v); else o1[idx & 7] = f2bfu(v);
      }
    u16* dst = Out + ((size_t)(cbt * 32 + s * 16 + fr)) * 64 + kg * 16;
    *(u16x8*)dst       = o0;
    *(u16x8*)(dst + 8) = o1;

    bt = btl;
  }
}

// ---------------------------------------------------------------- stage 2 ---
// Grid: 512 blocks = 8 b * 2 nt * 2 jt * 16 kc. Block = 4 waves (2x2), tile 128x128.
__global__ __launch_bounds__(256, 2) void k_phase2(
    const u16* __restrict__ A, const u16* __restrict__ Bm,
    float* __restrict__ C)
{
  __shared__ __align__(16) u16 Alds[128 * 64];
  __shared__ __align__(16) u16 Blds[128 * 64];

  const int tid  = threadIdx.x;
  const int lane = tid & 63;
  const int wave = tid >> 6;
  const int fr   = lane & 15;
  const int kg   = lane >> 4;

  const int bid = blockIdx.x;
  const int kc = bid & 15;
  const int jt = (bid >> 4) & 1;
  const int nt = (bid >> 5) & 1;
  const int b  = bid >> 6;          // [0,8) for 512 blocks
  const int n0 = nt * 128, j0 = jt * 128;
  const int wr = wave >> 1, wc = wave & 1;

  const u16* Ab = A  + (size_t)b * 4194304;
  const u16* Bb = Bm + (size_t)b * 4194304;

  f32x4 acc[4][4];
#pragma unroll
  for (int mt = 0; mt < 4; ++mt)
#pragma unroll
    for (int nn = 0; nn < 4; ++nn) {
      acc[mt][nn][0] = 0.f; acc[mt][nn][1] = 0.f; acc[mt][nn][2] = 0.f; acc[mt][nn][3] = 0.f;
    }

  for (int ii = 0; ii < 16; ++ii) {
    const int i = kc * 16 + ii;

    i32x4 va[4], vb[4];
#pragma unroll
    for (int rep = 0; rep < 4; ++rep) {
      int c = tid + rep * 256;
      int row = c >> 3, ch = c & 7;
      va[rep] = *(const i32x4*)(Ab + (size_t)(n0 + row) * 16384 + (size_t)i * 64 + ch * 8);
      vb[rep] = *(const i32x4*)(Bb + (size_t)i * 16384 + (size_t)(j0 + row) * 64 + ch * 8);
    }
    __syncthreads();
#pragma unroll
    for (int rep = 0; rep < 4; ++rep) {
      int c = tid + rep * 256;
      int row = c >> 3, ch = c & 7;
      int sw = ch ^ (row & 7);
      *(i32x4*)&Alds[row * 64 + sw * 8] = va[rep];
      *(i32x4*)&Blds[row * 64 + sw * 8] = vb[rep];
    }
    __syncthreads();

#pragma unroll
    for (int ks = 0; ks < 2; ++ks) {
      bf16x8 af[4], bfv[4];
#pragma unroll
      for (int mt = 0; mt < 4; ++mt) {
        int row = wr * 64 + mt * 16 + fr;
        int sw = (ks * 4 + kg) ^ (row & 7);
        af[mt] = *(const bf16x8*)&Alds[row * 64 + sw * 8];
      }
#pragma unroll
      for (int nn = 0; nn < 4; ++nn) {
        int row = wc * 64 + nn * 16 + fr;
        int sw = (ks * 4 + kg) ^ (row & 7);
        bfv[nn] = *(const bf16x8*)&Blds[row * 64 + sw * 8];
      }
#pragma unroll
      for (int mt = 0; mt < 4; ++mt)
#pragma unroll
        for (int nn = 0; nn < 4; ++nn)
          acc[mt][nn] = __builtin_amdgcn_mfma_f32_16x16x32_bf16(af[mt], bfv[nn], acc[mt][nn], 0, 0, 0);
    }
  }

  float* Cb = C + ((size_t)b << 16);
#pragma unroll
  for (int mt = 0; mt < 4; ++mt)
#pragma unroll
    for (int nn = 0; nn < 4; ++nn)
#pragma unroll
      for (int r = 0; r < 4; ++r) {
        int n = n0 + wr * 64 + mt * 16 + kg * 4 + r;
        int j = j0 + wc * 64 + nn * 16 + fr;
        atomicAdd(&Cb[n * 256 + j], acc[mt][nn][r] * 0.02f);
      }
}

// ------------------------------------------------------------------ launch --
extern "C" void kernel_launch(void* const* d_in, const int* in_sizes, int n_in,
                              void* d_out, int out_size, void* d_ws, size_t ws_size,
                              hipStream_t stream)
{
  const float* rbf0 = (const float*)d_in[0];
  const float* rbfd = (const float*)d_in[1];
  const float* Q0w  = (const float*)d_in[2];
  const float* Q0b  = (const float*)d_in[3];
  const float* Qw   = (const float*)d_in[4];
  const float* Qb   = (const float*)d_in[5];
  const float* R0w  = (const float*)d_in[6];
  const float* R0b  = (const float*)d_in[7];
  const float* Rw   = (const float*)d_in[8];
  const float* Rb   = (const float*)d_in[9];
  float* out = (float*)d_out;

  u16* Abuf = (u16*)d_ws;
  u16* Bbuf = Abuf + (size_t)33554432;

  hipMemsetAsync(d_out, 0, (size_t)out_size * sizeof(float), stream);
  hipLaunchKernelGGL(k_phase1, dim3(2048), dim3(256), 0, stream,
                     rbf0, rbfd, Q0w, Q0b, Qw, Qb, R0w, R0b, Rw, Rb, Abuf, Bbuf);
  hipLaunchKernelGGL(k_phase2, dim3(512), dim3(256), 0, stream, Abuf, Bbuf, out);
}